// Round 3
// baseline (37.760 us; speedup 1.0000x reference)
//
#include <hip/hip_runtime.h>

// AnchorProcessor: x[8,255,128,128] f32 -> out[8,18,128,128] f32
// v3: float4 loads + high occupancy. One block = one anchor a, 32 pixels.
// Block 256 = {q=wave 0..3 (class quarter), n=0..7, p=0..7 (x float4 pixels)}.
// Grid = 3 * 512 = 1536 blocks -> 6 blocks/CU, 24 waves/CU.
// Cross-(n,q) max/argmax combine in LDS, flat-index (n*80+c) first-max tie-break.

#define NN   8
#define AA   3
#define CLSN 80
#define HW   16384           // 128*128
#define CH   255             // 3*85

__device__ __forceinline__ float sigf(float v) {
    return 1.0f / (1.0f + __expf(-v));
}

__global__ __launch_bounds__(256)
void anchor_kernel_v3(const float* __restrict__ x, float* __restrict__ out) {
    const int tid = threadIdx.x;
    const int p   = tid & 7;             // 8 lane-groups x float4 = 32 pixels
    const int n   = (tid >> 3) & 7;
    const int q   = tid >> 6;            // wave index = class quarter (uniform)

    const int bid      = blockIdx.x;
    const int pixblock = bid & 511;      // 512 pixel-blocks
    const int a        = bid >> 9;       // 0..2
    const int pix      = pixblock * 32 + p * 4;
    const int h        = pix >> 7;
    const int w0       = pix & 127;

    const float anchw[AA] = {116.f, 156.f, 373.f};
    const float anchh[AA] = { 90.f, 198.f, 326.f};

    const int abase = n * (CH * HW) + (a * 85) * HW + pix;

    __shared__ float4 s_val[NN][4][8];
    __shared__ int4   s_idx[NN][4][8];

    const float4 obj = *(const float4*)(x + abase + 4 * HW);

    if (q == 0) {   // wave-uniform: boxes
        const float4 tx = *(const float4*)(x + abase + 0 * HW);
        const float4 ty = *(const float4*)(x + abase + 1 * HW);
        const float4 tw = *(const float4*)(x + abase + 2 * HW);
        const float4 th = *(const float4*)(x + abase + 3 * HW);
        float4 bx, by, bw, bh;
        bx.x = sigf(tx.x) + (float)(w0 + 0);
        bx.y = sigf(tx.y) + (float)(w0 + 1);
        bx.z = sigf(tx.z) + (float)(w0 + 2);
        bx.w = sigf(tx.w) + (float)(w0 + 3);
        const float fh = (float)h;
        by.x = sigf(ty.x) + fh;  by.y = sigf(ty.y) + fh;
        by.z = sigf(ty.z) + fh;  by.w = sigf(ty.w) + fh;
        bw.x = tw.x * anchw[a];  bw.y = tw.y * anchw[a];
        bw.z = tw.z * anchw[a];  bw.w = tw.w * anchw[a];
        bh.x = th.x * anchh[a];  bh.y = th.y * anchh[a];
        bh.z = th.z * anchh[a];  bh.w = th.w * anchh[a];
        const int obase = (n * 18 + a * 6) * HW + pix;
        *(float4*)(out + obase + 0 * HW) = bx;
        *(float4*)(out + obase + 1 * HW) = by;
        *(float4*)(out + obase + 2 * HW) = bw;
        *(float4*)(out + obase + 3 * HW) = bh;
    }

    // 20-class partial reduction (flat idx = n*80 + q*20 + c, first-max)
    float4 best = make_float4(-__builtin_inff(), -__builtin_inff(),
                              -__builtin_inff(), -__builtin_inff());
    int4 bidx = make_int4(0x7fffffff, 0x7fffffff, 0x7fffffff, 0x7fffffff);
    const int cbeg = 5 + q * 20;
    const int ibeg = n * CLSN + q * 20;
    #pragma unroll 4
    for (int c = 0; c < 20; ++c) {
        float4 v = *(const float4*)(x + abase + (cbeg + c) * HW);
        v.x *= obj.x; v.y *= obj.y; v.z *= obj.z; v.w *= obj.w;
        const int id = ibeg + c;
        if (v.x > best.x) { best.x = v.x; bidx.x = id; }
        if (v.y > best.y) { best.y = v.y; bidx.y = id; }
        if (v.z > best.z) { best.z = v.z; bidx.z = id; }
        if (v.w > best.w) { best.w = v.w; bidx.w = id; }
    }
    s_val[n][q][p] = best;
    s_idx[n][q][p] = bidx;
    __syncthreads();

    // combine 32 partials per pixel4; waves 1 and 2 write smax / sarg.
    if (q == 1 || q == 2) {
        float4 fbest = make_float4(-__builtin_inff(), -__builtin_inff(),
                                   -__builtin_inff(), -__builtin_inff());
        int4 fidx = make_int4(0x7fffffff, 0x7fffffff, 0x7fffffff, 0x7fffffff);
        #pragma unroll
        for (int nn = 0; nn < NN; ++nn) {
            #pragma unroll
            for (int qq = 0; qq < 4; ++qq) {
                const float4 v  = s_val[nn][qq][p];
                const int4   id = s_idx[nn][qq][p];
                if (v.x > fbest.x || (v.x == fbest.x && id.x < fidx.x)) { fbest.x = v.x; fidx.x = id.x; }
                if (v.y > fbest.y || (v.y == fbest.y && id.y < fidx.y)) { fbest.y = v.y; fidx.y = id.y; }
                if (v.z > fbest.z || (v.z == fbest.z && id.z < fidx.z)) { fbest.z = v.z; fidx.z = id.z; }
                if (v.w > fbest.w || (v.w == fbest.w && id.w < fidx.w)) { fbest.w = v.w; fidx.w = id.w; }
            }
        }
        const int obase = (n * 18 + a * 6) * HW + pix;
        if (q == 1) {
            *(float4*)(out + obase + 4 * HW) = fbest;
        } else {
            float4 f;
            f.x = (float)fidx.x; f.y = (float)fidx.y;
            f.z = (float)fidx.z; f.w = (float)fidx.w;
            *(float4*)(out + obase + 5 * HW) = f;
        }
    }
}

extern "C" void kernel_launch(void* const* d_in, const int* in_sizes, int n_in,
                              void* d_out, int out_size, void* d_ws, size_t ws_size,
                              hipStream_t stream) {
    const float* x = (const float*)d_in[0];
    float* out = (float*)d_out;
    dim3 grid(3 * 512);   // a * pixel-blocks
    dim3 block(256);
    hipLaunchKernelGGL(anchor_kernel_v3, grid, block, 0, stream, x, out);
}

// Round 4
// 27.607 us; speedup vs baseline: 1.3678x; 1.3678x over previous
//
#include <hip/hip_runtime.h>

// AnchorProcessor: x[8,255,128,128] f32 -> out[8,18,128,128] f32
// v4: channel-conflict-free. Wave w owns batch n=w; lane = 1 of 64 consecutive
// pixels -> every load instruction is ONE contiguous 256B segment (no same-
// channel scatter across n-regions). Block 512 thr = 8 waves (all n); grid =
// 3 anchors x 256 pixel-groups = 768 blocks = 3 blocks/CU = 24 waves/CU.
// Per-(a,pixel) max/argmax over (n,c) completes in-block via LDS, first-max
// tie-break on flat idx n*80+c.

#define NN   8
#define AA   3
#define CLSN 80
#define HW   16384           // 128*128
#define CH   255             // 3*85

__device__ __forceinline__ float sigf(float v) {
    return 1.0f / (1.0f + __expf(-v));
}

__global__ __launch_bounds__(512, 6)
void anchor_kernel_v4(const float* __restrict__ x, float* __restrict__ out) {
    const int lane = threadIdx.x & 63;     // pixel within 64-pixel group
    const int n    = threadIdx.x >> 6;     // wave id = batch index

    const int bid = blockIdx.x;
    const int a   = bid >> 8;              // 0..2
    const int pg  = bid & 255;             // 256 pixel-groups
    const int pix = pg * 64 + lane;        // flat pixel h*128+w
    const int h   = pix >> 7;
    const int w   = pix & 127;

    const float anchw[AA] = {116.f, 156.f, 373.f};
    const float anchh[AA] = { 90.f, 198.f, 326.f};

    const int abase = n * (CH * HW) + (a * 85) * HW + pix;

    // boxes + objectness (5 independent loads up front)
    const float tx  = x[abase + 0 * HW];
    const float ty  = x[abase + 1 * HW];
    const float tw  = x[abase + 2 * HW];
    const float th  = x[abase + 3 * HW];
    const float obj = x[abase + 4 * HW];

    const int obase = (n * 18 + a * 6) * HW + pix;
    out[obase + 0 * HW] = sigf(tx) + (float)w;
    out[obase + 1 * HW] = sigf(ty) + (float)h;
    out[obase + 2 * HW] = tw * anchw[a];
    out[obase + 3 * HW] = th * anchh[a];

    // 80-class partial reduction for this n (flat idx = n*80+c, first-max)
    float best = -__builtin_inff();
    int   bidx = 0x7fffffff;
    #pragma unroll 8
    for (int c = 0; c < CLSN; ++c) {
        const float v = x[abase + (5 + c) * HW] * obj;
        if (v > best) { best = v; bidx = n * CLSN + c; }
    }

    __shared__ float s_val[NN][64];
    __shared__ int   s_idx[NN][64];
    s_val[n][lane] = best;
    s_idx[n][lane] = bidx;
    __syncthreads();

    // cross-n combine; identical result for all waves, each writes its own n.
    float fbest = s_val[0][lane];
    int   fidx  = s_idx[0][lane];
    #pragma unroll
    for (int nn = 1; nn < NN; ++nn) {
        const float v  = s_val[nn][lane];
        const int   id = s_idx[nn][lane];
        if (v > fbest || (v == fbest && id < fidx)) { fbest = v; fidx = id; }
    }
    out[obase + 4 * HW] = fbest;
    out[obase + 5 * HW] = (float)fidx;
}

extern "C" void kernel_launch(void* const* d_in, const int* in_sizes, int n_in,
                              void* d_out, int out_size, void* d_ws, size_t ws_size,
                              hipStream_t stream) {
    const float* x = (const float*)d_in[0];
    float* out = (float*)d_out;
    dim3 grid(AA * 256);   // anchor x pixel-group
    dim3 block(512);
    hipLaunchKernelGGL(anchor_kernel_v4, grid, block, 0, stream, x, out);
}